// Round 9
// baseline (49.986 us; speedup 1.0000x reference)
//
#include <hip/hip_runtime.h>
#include <math.h>

#define BB 4
#define NN 512
#define PP 2048
#define EE 32768
#define FH 128
#define DRBF 32
#define INDIM 416
#define CUT 4.0f
#define PI_F 3.14159265358979323846f
#define HP 424            // padded hS row (floats)
#define NE 4              // edges per MLP iteration
#define CHUNK 512         // raw edges per block

// Node 1: zero the 8192-float output. 8 blocks x 256 threads x float4.
__global__ __launch_bounds__(256) void init_out(float* __restrict__ out) {
  int i = blockIdx.x * 256 + threadIdx.x;
  ((float4*)out)[i] = make_float4(0.f, 0.f, 0.f, 0.f);
}

// Node 2: fused filter + gather + MLP. Block = 256 threads / 4 waves owns 512
// raw edges; survivors kept in LDS (no global round-trip, no cnt dependency);
// MLP: L1 thread=(f1 in 128, k-half), 16-deep ping-pong weight regs; L2
// wave=edge lane=feature; L3 shfl-reduce + 1 atomic per edge.
__global__ __launch_bounds__(256) void fused_kernel(
    const int* __restrict__ pe, const float* __restrict__ pdisp,
    const float* __restrict__ cell, const float* __restrict__ atom_xyz,
    const float* __restrict__ probe_xyz,
    const float* __restrict__ S, const float* __restrict__ V,
    const float* __restrict__ W1, const float* __restrict__ b1,
    const float* __restrict__ W2, const float* __restrict__ b2,
    const float* __restrict__ W3, const float* __restrict__ b3,
    float* __restrict__ out) {
  __shared__ float sdx[CHUNK], sdy[CHUNK], sdz[CHUNK];   // 6 KB
  __shared__ unsigned sap[CHUNK];                        // 2 KB
  __shared__ int mcnt;
  __shared__ float hS[NE][HP];                           // 6.8 KB
  __shared__ float h2S[NE][FH];                          // 2 KB
  __shared__ float part[NE][FH];                         // 2 KB
  __shared__ float cwS[NE];
  __shared__ unsigned pS[NE];

  const int t    = threadIdx.x;
  const int lane = t & 63;
  const int wave = t >> 6;
  if (t == 0) mcnt = 0;
  __syncthreads();

  // ---------- Phase F: filter this block's 512 edges ----------
  const int base = blockIdx.x * CHUNK;
  const int b = base >> 15;           // chunk never crosses a batch
  const float* cb = cell + b * 9;     // wave-uniform -> scalar
  const float c00=cb[0],c01=cb[1],c02=cb[2],
              c10=cb[3],c11=cb[4],c12=cb[5],
              c20=cb[6],c21=cb[7],c22=cb[8];
  #pragma unroll
  for (int i = 0; i < 2; ++i) {
    const int e = base + t + i * 256;
    int2 ap = ((const int2*)pe)[e];
    float pd0 = pdisp[e*3], pd1 = pdisp[e*3+1], pd2 = pdisp[e*3+2];
    float d0 = pd0*c00 + pd1*c10 + pd2*c20;
    float d1 = pd0*c01 + pd1*c11 + pd2*c21;
    float d2 = pd0*c02 + pd1*c12 + pd2*c22;
    int ag = b*NN + ap.x;
    int pg = b*PP + ap.y;
    float dx = probe_xyz[pg*3]   - (atom_xyz[ag*3]   + d0);
    float dy = probe_xyz[pg*3+1] - (atom_xyz[ag*3+1] + d1);
    float dz = probe_xyz[pg*3+2] - (atom_xyz[ag*3+2] + d2);
    float dist2 = dx*dx + dy*dy + dz*dz;
    if (dist2 < CUT*CUT) {
      int s = atomicAdd(&mcnt, 1);   // LDS atomic
      sdx[s] = dx; sdy[s] = dy; sdz[s] = dz;
      sap[s] = ((unsigned)ag << 16) | (unsigned)pg;
    }
  }
  __syncthreads();
  const int m = mcnt;
  if (m == 0) return;

  const float2* Vf2 = (const float2*)V;
  const float2* Sf2 = (const float2*)S;
  const int f1 = t & 127;     // layer1 output feature
  const int kh = t >> 7;      // k-half: 0 -> k 0..207, 1 -> 208..415
  const float b1v = b1[f1];
  const float b2v = b2[lane];
  const float w3v = W3[lane];
  const float b3v = b3[0];

  // ---------- Phase M: MLP over local survivors, NE at a time ----------
  for (int s0 = 0; s0 < m; s0 += NE) {
    // gather: wave w builds h for survivor s0+w (LDS record, broadcast read)
    {
      const int s = s0 + wave;
      float dx, dy, dz; unsigned ap_;
      if (s < m) { dx = sdx[s]; dy = sdy[s]; dz = sdz[s]; ap_ = sap[s]; }
      else       { dx = 1.f; dy = 0.f; dz = 0.f; ap_ = 0xFFFFFFFFu; }
      unsigned a = (ap_ == 0xFFFFFFFFu) ? 0u : (ap_ >> 16);
      float2 v0 = Vf2[(a*3+0)*64 + lane];
      float2 v1 = Vf2[(a*3+1)*64 + lane];
      float2 v2 = Vf2[(a*3+2)*64 + lane];
      float2 sj = Sf2[a*64 + lane];
      float d = sqrtf(dx*dx + dy*dy + dz*dz);
      float inv = 1.0f / (d + 1e-8f);
      float rh0 = dx*inv, rh1 = dy*inv, rh2 = dz*inv;
      if (lane < DRBF) hS[wave][lane] = sinf(d * (float)(lane+1) * (PI_F/CUT)) / d;
      float2 q;  q.x  = v0.x*rh0 + v1.x*rh1 + v2.x*rh2;
                 q.y  = v0.y*rh0 + v1.y*rh1 + v2.y*rh2;
      float2 nv; nv.x = sqrtf(v0.x*v0.x + v1.x*v1.x + v2.x*v2.x);
                 nv.y = sqrtf(v0.y*v0.y + v1.y*v1.y + v2.y*v2.y);
      *(float2*)&hS[wave][DRBF        + 2*lane] = q;
      *(float2*)&hS[wave][DRBF +   FH + 2*lane] = nv;
      *(float2*)&hS[wave][DRBF + 2*FH + 2*lane] = sj;
      if (lane == 0) {
        cwS[wave] = 0.5f * (cosf((PI_F/CUT) * d) + 1.0f);
        pS[wave]  = (ap_ == 0xFFFFFFFFu) ? 0xFFFFFFFFu : (ap_ & 0xFFFFu);
      }
    }
    __syncthreads();

    // ----- layer 1: 13 ping-pong groups of 16 k's per k-half -----
    {
      float acc0, acc1, acc2, acc3;
      acc0 = acc1 = acc2 = acc3 = (kh == 0) ? b1v : 0.0f;
      const float* Wb = W1 + f1;
      const int kbase = kh * 208;

      #define L1G(wbuf, kk)                                                        \
        { _Pragma("unroll")                                                        \
          for (int q = 0; q < 4; ++q) {                                            \
            float4 h0 = *(const float4*)&hS[0][(kk) + q*4];                        \
            float4 h1 = *(const float4*)&hS[1][(kk) + q*4];                        \
            float4 h2_ = *(const float4*)&hS[2][(kk) + q*4];                       \
            float4 h3 = *(const float4*)&hS[3][(kk) + q*4];                        \
            acc0 = fmaf(h0.x, wbuf[q*4+0], acc0); acc1 = fmaf(h1.x, wbuf[q*4+0], acc1); \
            acc2 = fmaf(h2_.x, wbuf[q*4+0], acc2); acc3 = fmaf(h3.x, wbuf[q*4+0], acc3); \
            acc0 = fmaf(h0.y, wbuf[q*4+1], acc0); acc1 = fmaf(h1.y, wbuf[q*4+1], acc1); \
            acc2 = fmaf(h2_.y, wbuf[q*4+1], acc2); acc3 = fmaf(h3.y, wbuf[q*4+1], acc3); \
            acc0 = fmaf(h0.z, wbuf[q*4+2], acc0); acc1 = fmaf(h1.z, wbuf[q*4+2], acc1); \
            acc2 = fmaf(h2_.z, wbuf[q*4+2], acc2); acc3 = fmaf(h3.z, wbuf[q*4+2], acc3); \
            acc0 = fmaf(h0.w, wbuf[q*4+3], acc0); acc1 = fmaf(h1.w, wbuf[q*4+3], acc1); \
            acc2 = fmaf(h2_.w, wbuf[q*4+3], acc2); acc3 = fmaf(h3.w, wbuf[q*4+3], acc3); \
          } }

      float wA[16], wB[16];
      #pragma unroll
      for (int i = 0; i < 16; ++i) wA[i] = Wb[(kbase + i)*FH];

      #pragma unroll 1
      for (int p = 0; p < 6; ++p) {
        const int kA = kbase + 2*p*16, kB = kA + 16;
        #pragma unroll
        for (int i = 0; i < 16; ++i) wB[i] = Wb[(kB + i)*FH];
        L1G(wA, kA);
        if (p < 6) {
          #pragma unroll
          for (int i = 0; i < 16; ++i) wA[i] = Wb[(kA + 32 + i)*FH];
        }
        L1G(wB, kB);
      }
      L1G(wA, kbase + 192);   // 13th group

      #undef L1G

      if (kh == 1) {
        part[0][f1] = acc0; part[1][f1] = acc1;
        part[2][f1] = acc2; part[3][f1] = acc3;
      }
      __syncthreads();
      if (kh == 0) {
        float z0 = acc0 + part[0][f1];
        float z1 = acc1 + part[1][f1];
        float z2 = acc2 + part[2][f1];
        float z3 = acc3 + part[3][f1];
        h2S[0][f1] = z0 / (1.0f + __expf(-z0));
        h2S[1][f1] = z1 / (1.0f + __expf(-z1));
        h2S[2][f1] = z2 / (1.0f + __expf(-z2));
        h2S[3][f1] = z3 / (1.0f + __expf(-z3));
      }
    }
    __syncthreads();

    // ----- layer 2: wave = edge, lane = feature; ping-pong groups -----
    float acc2 = b2v;
    {
      const float* Wp = W2 + lane;
      const float* hp = &h2S[wave][0];
      #define L2G(wbuf, kk)                                        \
        { _Pragma("unroll")                                        \
          for (int q = 0; q < 4; ++q) {                            \
            float4 hv = *(const float4*)(hp + (kk) + q*4);         \
            acc2 = fmaf(hv.x, wbuf[q*4+0], acc2);                  \
            acc2 = fmaf(hv.y, wbuf[q*4+1], acc2);                  \
            acc2 = fmaf(hv.z, wbuf[q*4+2], acc2);                  \
            acc2 = fmaf(hv.w, wbuf[q*4+3], acc2);                  \
          } }
      float wA[16], wB[16];
      #pragma unroll
      for (int i = 0; i < 16; ++i) wA[i] = Wp[i*64];
      #pragma unroll 1
      for (int p = 0; p < 4; ++p) {
        const int kA = p*32, kB = p*32 + 16;
        #pragma unroll
        for (int i = 0; i < 16; ++i) wB[i] = Wp[(kB + i)*64];
        L2G(wA, kA);
        if (p < 3) {
          #pragma unroll
          for (int i = 0; i < 16; ++i) wA[i] = Wp[(kA + 32 + i)*64];
        }
        L2G(wB, kB);
      }
      #undef L2G
    }

    // ----- layer 3: silu, dot with W3 across lanes, scatter -----
    {
      float h2 = acc2 / (1.0f + __expf(-acc2));
      float rs = h2 * w3v;
      #pragma unroll
      for (int off = 32; off; off >>= 1) rs += __shfl_xor(rs, off, 64);
      if (lane == 0) {
        unsigned p = pS[wave];
        if (p != 0xFFFFFFFFu) atomicAdd(&out[p], (rs + b3v) * cwS[wave]);
      }
    }
    __syncthreads();   // protect hS/h2S/part before next iteration
  }
}

extern "C" void kernel_launch(void* const* d_in, const int* in_sizes, int n_in,
                              void* d_out, int out_size, void* d_ws, size_t ws_size,
                              hipStream_t stream) {
  const float* S         = (const float*)d_in[0];
  const float* V         = (const float*)d_in[1];
  const float* atom_xyz  = (const float*)d_in[2];
  const float* probe_xyz = (const float*)d_in[3];
  const float* cell      = (const float*)d_in[4];
  const float* pdisp     = (const float*)d_in[5];
  const float* W1        = (const float*)d_in[6];
  const float* b1        = (const float*)d_in[7];
  const float* W2        = (const float*)d_in[8];
  const float* b2        = (const float*)d_in[9];
  const float* W3        = (const float*)d_in[10];
  const float* b3        = (const float*)d_in[11];
  const int*   pe        = (const int*)d_in[12];
  float* out = (float*)d_out;

  init_out<<<8, 256, 0, stream>>>(out);
  fused_kernel<<<BB*EE/CHUNK, 256, 0, stream>>>(pe, pdisp, cell, atom_xyz, probe_xyz,
                                                S, V, W1, b1, W2, b2, W3, b3, out);
}